// Round 12
// baseline (115.269 us; speedup 1.0000x reference)
//
#include <hip/hip_runtime.h>

// Problem constants (fixed shapes from the reference).
constexpr int B = 2, C = 320, H = 128, W = 240;
constexpr int G = 40, CPG = 8, MAXD = 48;
constexpr int HW = H * W;
constexpr int NROW = B * G * H;        // 10240 (b,g,h) rows
constexpr int ROWS_PER_BLOCK = 8;      // 8 waves/block, one row each, consecutive h
constexpr int W4 = W / 4;              // 60 float4 per channel row
constexpr int NBLK = NROW / ROWS_PER_BLOCK;  // 1280
constexpr int NXCD = 8;                // 1280 % 8 == 0 -> simple swizzle bijective

typedef float f32x4 __attribute__((ext_vector_type(4)));

// Address-space-qualified void types for global_load_lds.
typedef const __attribute__((address_space(1))) void g_void;
typedef __attribute__((address_space(3))) void lds_void;

// sched_barrier masks (LLVM SchedGroupMask): ALU=0x1 VALU=0x2 SALU=0x4
// VMEM_WRITE=0x40 DS_READ=0x100.
// Leading barrier (cross-wave wb visibility): only ALU/VALU/SALU may cross —
//   wb DS_READs must stay after it.
// Trailing barrier (wb reuse): additionally DS_READ (sR4 compute reads of the
//   NEXT dg) and VMEM_WRITE (in-flight nt stores) may cross — wb DS_WRITEs
//   of the next phase must stay after it.
#define SB_LEAD  0x7
#define SB_TRAIL 0x147

// out[b,g,d,h,x] = (1/CPG) * sum_k L[b, g*CPG+k, h, x] * R[b, g*CPG+k, h, x-d]  (x>=d, else 0)
//
// R12 = R11 (114.75us: R7 + XCD swizzle) + masked sched_barriers so the
// compiler may overlap the NEXT dg's compute (VALU + sR4 DS_READs, which
// never touch wb) with the current store phases, + Lv pre-scaled by 1/CPG
// at load (drops 192 VALU muls/lane from the acc->wb critical path).
__global__ __launch_bounds__(512) void gwc_volume_kernel(
    const float* __restrict__ left, const float* __restrict__ right,
    float* __restrict__ out)
{
    const int tid  = threadIdx.x;
    const int wv   = tid >> 6;   // wave id within block -> which row (0..7)
    const int lane = tid & 63;

    // XCD swizzle: logical block id (bijective, 1280 = 8 * 160).
    const int bid  = blockIdx.x;
    const int lbid = (bid & (NXCD - 1)) * (NBLK / NXCD) + (bid >> 3);
    const int row  = lbid * ROWS_PER_BLOCK + wv;

    const int h  = row % H;
    const int h0 = h - wv;       // block's first h row (8 | H, never straddles (b,g))
    const int bg = row / H;
    const int g  = bg % G;
    const int b  = bg / G;

    // Staged right rows: 8 waves x 480 float4 = 61.4 KB (linear, gload_lds dest).
    __shared__ f32x4 sR4[ROWS_PER_BLOCK][CPG * W4];
    // Write-coalescing buffer for one dd-pair: [ddl][row][x4] = 15.4 KB.
    __shared__ f32x4 wb[2][ROWS_PER_BLOCK][W4];

    const size_t in_base = ((size_t)(b * C + g * CPG) * H + h) * (size_t)W;

    const int t = lane;                  // x-tile index, x = 4t..4t+3
    const bool active = (t < W4);        // lanes 60..63: staging + coop store only

    // ---- issue LEFT loads first (registers), so they fly with R staging ----
    f32x4 Lv[CPG];
    if (active) {
        #pragma unroll
        for (int k = 0; k < CPG; ++k)
            Lv[k] = __builtin_nontemporal_load(
                reinterpret_cast<const f32x4*>(left + in_base + (size_t)k * HW + 4 * t));
    }

    // ---- stage RIGHT row: direct HBM -> LDS, 8 x (64 lanes x 16 B) chunks ----
    #pragma unroll
    for (int i = 0; i < 8; ++i) {
        const int j = i * 64 + lane;     // float4 index: j = k*60 + x4
        if (j < CPG * W4) {
            const int k  = j / W4;
            const int x4 = j - k * W4;
            const float* src = right + in_base + (size_t)k * HW + 4 * x4;
            char* dst = (char*)&sR4[wv][0] + (size_t)i * 1024;
            __builtin_amdgcn_global_load_lds((g_void*)src, (lds_void*)dst, 16, 0, 0);
        }
    }

    // One drain for BOTH batches (L regs + LDS staging), then compute.
    asm volatile("s_waitcnt vmcnt(0)" ::: "memory");
    __builtin_amdgcn_sched_barrier(0);

    // Pre-scale L by 1/CPG: acc comes out already scaled (error << threshold).
    if (active) {
        #pragma unroll
        for (int k = 0; k < CPG; ++k) Lv[k] *= 0.125f;
    }

    const f32x4* sr = &sR4[wv][0];
    const f32x4* wbflat = &wb[0][0][0];
    // Base (in floats) of the block's 8-row chunk in d-slice 0 of this (b,g).
    const size_t chunk00 = ((size_t)bg * MAXD * H + h0) * (size_t)W;

    // ---- 12 disparity groups of 4 ----
    #pragma unroll 1
    for (int dg = 0; dg < MAXD / 4; ++dg) {
        float acc[4][4];
        #pragma unroll
        for (int dd = 0; dd < 4; ++dd)
            #pragma unroll
            for (int xx = 0; xx < 4; ++xx) acc[dd][xx] = 0.f;

        if (active && t >= dg) {         // t < dg: whole tile in the zero wedge
            #pragma unroll
            for (int k = 0; k < CPG; ++k) {
                const int base = k * W4 + (t - dg);
                const f32x4 hi = sr[base];                   // R[A .. A+3]
                f32x4 lo;
                if (t > dg) lo = sr[base - 1];               // R[A-4 .. A-1]
                else        lo = (f32x4){0.f, 0.f, 0.f, 0.f}; // x<d -> zeros
                float win[8];
                win[0] = lo.x; win[1] = lo.y; win[2] = lo.z; win[3] = lo.w;
                win[4] = hi.x; win[5] = hi.y; win[6] = hi.z; win[7] = hi.w;
                // r-index = A + xx - dd -> win[4 + xx - dd]
                #pragma unroll
                for (int dd = 0; dd < 4; ++dd)
                    #pragma unroll
                    for (int xx = 0; xx < 4; ++xx)
                        acc[dd][xx] += Lv[k][xx] * win[4 + xx - dd];
            }
        }

        // ---- two dd-pair writeback phases through LDS ----
        #pragma unroll
        for (int phase = 0; phase < 2; ++phase) {
            if (active) {
                #pragma unroll
                for (int ddl = 0; ddl < 2; ++ddl) {
                    const int dd = phase * 2 + ddl;
                    f32x4 o;
                    o.x = acc[dd][0];
                    o.y = acc[dd][1];
                    o.z = acc[dd][2];
                    o.w = acc[dd][3];
                    wb[ddl][wv][t] = o;
                }
            }
            asm volatile("s_waitcnt lgkmcnt(0)" ::: "memory");
            __builtin_amdgcn_s_barrier();
            __builtin_amdgcn_sched_barrier(SB_LEAD);   // wb reads stay below

            // Cooperative dense store: 960 f32x4 (2 slices x 8 rows x 960B),
            // tid-linear -> full 1024B-aligned 64-lane nt bursts.
            const int d_base = dg * 4 + phase * 2;
            const size_t cbase = chunk00 + (size_t)d_base * HW;  // floats
            {
                const int f   = tid;                 // 0..511
                const int ddl = f / 480;
                const int rem = f - ddl * 480;
                const f32x4 v = wbflat[f];
                __builtin_nontemporal_store(
                    v, reinterpret_cast<f32x4*>(out + cbase + (size_t)ddl * HW + 4 * rem));
            }
            if (tid < 960 - 512) {                   // second sweep: f = tid+512
                const int f   = tid + 512;           // 512..959 -> ddl=1
                const int rem = f - 480;
                const f32x4 v = wbflat[f];
                __builtin_nontemporal_store(
                    v, reinterpret_cast<f32x4*>(out + cbase + (size_t)HW + 4 * rem));
            }

            asm volatile("s_waitcnt lgkmcnt(0)" ::: "memory");
            __builtin_amdgcn_s_barrier();            // wb reusable next phase
            __builtin_amdgcn_sched_barrier(SB_TRAIL); // next-dg compute may cross
        }
    }
}

extern "C" void kernel_launch(void* const* d_in, const int* in_sizes, int n_in,
                              void* d_out, int out_size, void* d_ws, size_t ws_size,
                              hipStream_t stream) {
    const float* left  = (const float*)d_in[0];
    const float* right = (const float*)d_in[1];
    float* out = (float*)d_out;

    dim3 grid(NBLK);                    // 1280 blocks
    dim3 block(512);                    // 8 waves, 8 consecutive h rows of one (b,g)
    hipLaunchKernelGGL(gwc_volume_kernel, grid, block, 0, stream,
                       left, right, out);
}

// Round 13
// 114.822 us; speedup vs baseline: 1.0039x; 1.0039x over previous
//
#include <hip/hip_runtime.h>

// Problem constants (fixed shapes from the reference).
constexpr int B = 2, C = 320, H = 128, W = 240;
constexpr int G = 40, CPG = 8, MAXD = 48;
constexpr int HW = H * W;
constexpr int NROW = B * G * H;        // 10240 (b,g,h) rows
constexpr int ROWS_PER_BLOCK = 8;      // 8 waves/block, one row each, consecutive h
constexpr int W4 = W / 4;              // 60 float4 per channel row
constexpr int NBLK = NROW / ROWS_PER_BLOCK;  // 1280
constexpr int NXCD = 8;                // 1280 % 8 == 0 -> simple swizzle bijective

typedef float f32x4 __attribute__((ext_vector_type(4)));

// Address-space-qualified void types for global_load_lds.
typedef const __attribute__((address_space(1))) void g_void;
typedef __attribute__((address_space(3))) void lds_void;

// out[b,g,d,h,x] = (1/CPG) * sum_k L[b, g*CPG+k, h, x] * R[b, g*CPG+k, h, x-d]  (x>=d, else 0)
//
// FINAL (R11, verified best 114.75us = 5.48 TB/s effective on the 629MB
// traffic floor; 87% of the measured 6.29 TB/s copy ceiling).
// Verified-win ladder (each A/B'd single-variable on MI355X):
//  - nt loads + gload_lds staging, L-loads issued first, ONE vmcnt(0) head
//    (concurrent staging; no serial lgkm chain)         137 -> ~121
//  - raw s_barrier only (never drains vmcnt; stores stay in flight)
//  - nt cooperative dense stores via LDS wb buffer: 2 slices x 8 rows x
//    960B tid-linear = full 1024B-aligned 64-lane bursts 121 -> 117.7
//    (plain cached stores A/B'd: 135.7 -> nt is worth ~15%)
//  - bijective XCD swizzle: 16 blocks tiling one bg run in-phase on one
//    XCD; per-XCD write footprint one 59MB span           117.7 -> 114.75
// Pruned (regressed/neutral): 4-row & 16-row blocks, plain stores, sliding-
// window carry, masked sched_barriers, Lv pre-scale.
__global__ __launch_bounds__(512) void gwc_volume_kernel(
    const float* __restrict__ left, const float* __restrict__ right,
    float* __restrict__ out)
{
    const int tid  = threadIdx.x;
    const int wv   = tid >> 6;   // wave id within block -> which row (0..7)
    const int lane = tid & 63;

    // XCD swizzle: logical block id (bijective, 1280 = 8 * 160).
    const int bid  = blockIdx.x;
    const int lbid = (bid & (NXCD - 1)) * (NBLK / NXCD) + (bid >> 3);
    const int row  = lbid * ROWS_PER_BLOCK + wv;

    const int h  = row % H;
    const int h0 = h - wv;       // block's first h row (8 | H, never straddles (b,g))
    const int bg = row / H;
    const int g  = bg % G;
    const int b  = bg / G;

    // Staged right rows: 8 waves x 480 float4 = 61.4 KB (linear, gload_lds dest).
    __shared__ f32x4 sR4[ROWS_PER_BLOCK][CPG * W4];
    // Write-coalescing buffer for one dd-pair: [ddl][row][x4] = 15.4 KB.
    __shared__ f32x4 wb[2][ROWS_PER_BLOCK][W4];

    const size_t in_base = ((size_t)(b * C + g * CPG) * H + h) * (size_t)W;

    const int t = lane;                  // x-tile index, x = 4t..4t+3
    const bool active = (t < W4);        // lanes 60..63: staging + coop store only

    // ---- issue LEFT loads first (registers), so they fly with R staging ----
    f32x4 Lv[CPG];
    if (active) {
        #pragma unroll
        for (int k = 0; k < CPG; ++k)
            Lv[k] = __builtin_nontemporal_load(
                reinterpret_cast<const f32x4*>(left + in_base + (size_t)k * HW + 4 * t));
    }

    // ---- stage RIGHT row: direct HBM -> LDS, 8 x (64 lanes x 16 B) chunks ----
    #pragma unroll
    for (int i = 0; i < 8; ++i) {
        const int j = i * 64 + lane;     // float4 index: j = k*60 + x4
        if (j < CPG * W4) {
            const int k  = j / W4;
            const int x4 = j - k * W4;
            const float* src = right + in_base + (size_t)k * HW + 4 * x4;
            char* dst = (char*)&sR4[wv][0] + (size_t)i * 1024;
            __builtin_amdgcn_global_load_lds((g_void*)src, (lds_void*)dst, 16, 0, 0);
        }
    }

    // One drain for BOTH batches (L regs + LDS staging), then compute.
    asm volatile("s_waitcnt vmcnt(0)" ::: "memory");
    __builtin_amdgcn_sched_barrier(0);

    const f32x4* sr = &sR4[wv][0];
    const f32x4* wbflat = &wb[0][0][0];
    // Base (in floats) of the block's 8-row chunk in d-slice 0 of this (b,g).
    const size_t chunk00 = ((size_t)bg * MAXD * H + h0) * (size_t)W;

    // ---- 12 disparity groups of 4 ----
    #pragma unroll 1
    for (int dg = 0; dg < MAXD / 4; ++dg) {
        float acc[4][4];
        #pragma unroll
        for (int dd = 0; dd < 4; ++dd)
            #pragma unroll
            for (int xx = 0; xx < 4; ++xx) acc[dd][xx] = 0.f;

        if (active && t >= dg) {         // t < dg: whole tile in the zero wedge
            #pragma unroll
            for (int k = 0; k < CPG; ++k) {
                const int base = k * W4 + (t - dg);
                const f32x4 hi = sr[base];                   // R[A .. A+3]
                f32x4 lo;
                if (t > dg) lo = sr[base - 1];               // R[A-4 .. A-1]
                else        lo = (f32x4){0.f, 0.f, 0.f, 0.f}; // x<d -> zeros
                float win[8];
                win[0] = lo.x; win[1] = lo.y; win[2] = lo.z; win[3] = lo.w;
                win[4] = hi.x; win[5] = hi.y; win[6] = hi.z; win[7] = hi.w;
                // r-index = A + xx - dd -> win[4 + xx - dd]
                #pragma unroll
                for (int dd = 0; dd < 4; ++dd)
                    #pragma unroll
                    for (int xx = 0; xx < 4; ++xx)
                        acc[dd][xx] += Lv[k][xx] * win[4 + xx - dd];
            }
        }

        // ---- two dd-pair writeback phases through LDS ----
        #pragma unroll
        for (int phase = 0; phase < 2; ++phase) {
            if (active) {
                #pragma unroll
                for (int ddl = 0; ddl < 2; ++ddl) {
                    const int dd = phase * 2 + ddl;
                    f32x4 o;
                    o.x = acc[dd][0] * 0.125f;
                    o.y = acc[dd][1] * 0.125f;
                    o.z = acc[dd][2] * 0.125f;
                    o.w = acc[dd][3] * 0.125f;
                    wb[ddl][wv][t] = o;
                }
            }
            asm volatile("s_waitcnt lgkmcnt(0)" ::: "memory");
            __builtin_amdgcn_s_barrier();
            __builtin_amdgcn_sched_barrier(0);

            // Cooperative dense store: 960 f32x4 (2 slices x 8 rows x 960B),
            // tid-linear -> full 1024B-aligned 64-lane nt bursts.
            const int d_base = dg * 4 + phase * 2;
            const size_t cbase = chunk00 + (size_t)d_base * HW;  // floats
            {
                const int f   = tid;                 // 0..511
                const int ddl = f / 480;
                const int rem = f - ddl * 480;
                const f32x4 v = wbflat[f];
                __builtin_nontemporal_store(
                    v, reinterpret_cast<f32x4*>(out + cbase + (size_t)ddl * HW + 4 * rem));
            }
            if (tid < 960 - 512) {                   // second sweep: f = tid+512
                const int f   = tid + 512;           // 512..959 -> ddl=1
                const int rem = f - 480;
                const f32x4 v = wbflat[f];
                __builtin_nontemporal_store(
                    v, reinterpret_cast<f32x4*>(out + cbase + (size_t)HW + 4 * rem));
            }

            asm volatile("s_waitcnt lgkmcnt(0)" ::: "memory");
            __builtin_amdgcn_s_barrier();            // wb reusable next phase
            __builtin_amdgcn_sched_barrier(0);
        }
    }
}

extern "C" void kernel_launch(void* const* d_in, const int* in_sizes, int n_in,
                              void* d_out, int out_size, void* d_ws, size_t ws_size,
                              hipStream_t stream) {
    const float* left  = (const float*)d_in[0];
    const float* right = (const float*)d_in[1];
    float* out = (float*)d_out;

    dim3 grid(NBLK);                    // 1280 blocks
    dim3 block(512);                    // 8 waves, 8 consecutive h rows of one (b,g)
    hipLaunchKernelGGL(gwc_volume_kernel, grid, block, 0, stream,
                       left, right, out);
}